// Round 1
// baseline (489.233 us; speedup 1.0000x reference)
//
#include <hip/hip_runtime.h>
#include <math.h>

// CTreeC loss: DEPTH=7, V = 2^8-1 = 255 states, B=64, T=50, vocab=5000.
// One block (1 wave of 64 lanes) per batch element. Tree structure derived
// analytically from in-order numbering:
//   p = v+1
//   START  <=> p is a power of 2                     (in-degree 0, prev0 = 1)
//   END    <=> p + (p & -p) == 256                   (no outgoing edges)
//   OUT set = non-END nodes (247)
//   non-START x: s = ctz(p), j = x - 2^s, k = ctz(p & (p-1));
//     incoming sources = { j - 2^a : a = 0..k-1 }    (gather, <= 7 reads)

#define TT 50
#define BB 64
#define VOCAB 5000
#define NS 255
#define NSP 256
#define LOG_EPS_F (-64.0f)
#define EPS_F 1.6038109389511818e-28f  // exp(-64)

__device__ __forceinline__ float wred_max(float x) {
#pragma unroll
    for (int m = 32; m >= 1; m >>= 1) x = fmaxf(x, __shfl_xor(x, m));
    return x;
}
__device__ __forceinline__ float wred_sum(float x) {
#pragma unroll
    for (int m = 32; m >= 1; m >>= 1) x += __shfl_xor(x, m);
    return x;
}

__global__ __launch_bounds__(64) void ctreec_kernel(
    const float* __restrict__ log_probs,      // [255][64][5000] f32
    const int* __restrict__ targets,          // [50][64] i32
    const int* __restrict__ target_lengths,   // [64] i32
    float* __restrict__ out)                  // [64] f32
{
    const int b = blockIdx.x;
    const int lane = threadIdx.x;
    const int vbase = lane * 4;

    __shared__ float e_lds[TT * NSP];   // 51200 B: extracted[t][v]
    __shared__ float outv[NSP];
    __shared__ int tgts[TT];

    const int len = target_lengths[b];

    if (lane < TT) tgts[lane] = targets[lane * BB + b];
    __syncthreads();

    // ---- Phase 1: gather extracted[t][v] = log_probs[v][b][tgt_t] into LDS
    {
        const size_t bvoff = (size_t)b * VOCAB;
        float4* e_vec = (float4*)e_lds;
#pragma unroll 4
        for (int t = 0; t < len; ++t) {
            const float* base = log_probs + bvoff + (size_t)tgts[t];
            float4 val;
            val.x = base[(size_t)(vbase + 0) * (BB * VOCAB)];
            val.y = base[(size_t)(vbase + 1) * (BB * VOCAB)];
            val.z = base[(size_t)(vbase + 2) * (BB * VOCAB)];
            val.w = (vbase + 3 < NS) ? base[(size_t)(vbase + 3) * (BB * VOCAB)]
                                     : -1e30f;   // pad slot v=255
            e_vec[t * 64 + lane] = val;
        }
    }
    __syncthreads();

    // ---- Per-lane static tree structure for its 4 nodes
    bool isend[4], isout[4];
    int kk[4], jj[4];
    float prev[4];
#pragma unroll
    for (int i = 0; i < 4; ++i) {
        int v = vbase + i;
        int p = v + 1;
        bool valid = (v < NS);
        bool pw2 = (p & (p - 1)) == 0;
        bool e_ = valid && ((p + (p & (-p))) == 256);
        isend[i] = e_;
        isout[i] = valid && !e_;
        prev[i] = (valid && pw2) ? 1.0f : 0.0f;
        if (valid && !pw2) {
            int s = __ffs(p) - 1;          // ctz(p)
            int q = p & (p - 1);           // clear lowest set bit
            kk[i] = __ffs(q) - 1;          // ctz(q)
            jj[i] = v - (1 << s);
        } else {
            kk[i] = 0;
            jj[i] = 0;
        }
    }

    // ---- Phase 2: serial scan over t (uniform per block)
    const float4* e_vec = (const float4*)e_lds;
    float acc = 0.0f;
    for (int t = 0; t < len; ++t) {
        float4 e4 = e_vec[t * 64 + lane];
        float e[4] = {e4.x, e4.y, e4.z, e4.w};
        float lc[4];
#pragma unroll
        for (int i = 0; i < 4; ++i) {
            float pv = prev[i];
            float lp = (pv < EPS_F) ? LOG_EPS_F : logf(pv);
            lc[i] = lp + e[i];
        }

        if (t == len - 1) {
            // end contribution: logsumexp over the 8 END nodes
            float m = -INFINITY;
#pragma unroll
            for (int i = 0; i < 4; ++i)
                if (isend[i]) m = fmaxf(m, lc[i]);
            m = wred_max(m);
            float s = 0.0f;
#pragma unroll
            for (int i = 0; i < 4; ++i)
                if (isend[i]) s += expf(lc[i] - m);
            s = wred_sum(s);
            acc += m + logf(s);
        } else {
            // log_C = logsumexp over the 247 OUT nodes
            float m = -INFINITY;
#pragma unroll
            for (int i = 0; i < 4; ++i)
                if (isout[i]) m = fmaxf(m, lc[i]);
            m = wred_max(m);
            float s = 0.0f;
#pragma unroll
            for (int i = 0; i < 4; ++i)
                if (isout[i]) s += expf(lc[i] - m);
            s = wred_sum(s);
            float logC = m + logf(s);
            acc += logC;   // mid contribution (t+1 < len always implies t < T-1)

            // outgoing = exp_safe(lc - logC) for OUT nodes (others never read)
#pragma unroll
            for (int i = 0; i < 4; ++i) {
                float d = lc[i] - logC;
                outv[vbase + i] = (d < LOG_EPS_F) ? EPS_F : expf(d);
            }
            __syncthreads();

            // new_prev[x] = sum over its <=7 sources
#pragma unroll
            for (int i = 0; i < 4; ++i) {
                float np_ = 0.0f;
                int bj = jj[i];
                int n = kk[i];
                for (int a = 0; a < n; ++a) np_ += outv[bj - (1 << a)];
                prev[i] = np_;
            }
            __syncthreads();
        }
    }

    if (lane == 0) out[b] = -acc;
}

extern "C" void kernel_launch(void* const* d_in, const int* in_sizes, int n_in,
                              void* d_out, int out_size, void* d_ws, size_t ws_size,
                              hipStream_t stream) {
    const float* log_probs = (const float*)d_in[0];       // 255*64*5000
    const int* targets = (const int*)d_in[1];             // 50*64
    const int* target_lengths = (const int*)d_in[2];      // 64
    float* out = (float*)d_out;                           // 64

    ctreec_kernel<<<dim3(BB), dim3(64), 0, stream>>>(log_probs, targets,
                                                     target_lengths, out);
}

// Round 2
// 460.715 us; speedup vs baseline: 1.0619x; 1.0619x over previous
//
#include <hip/hip_runtime.h>
#include <math.h>

// CTreeC loss: DEPTH=7, V=255 states, B=64, T=50, vocab=5000.
// R2: split into (a) massively-parallel gather of extracted[b][t][v] into
// d_ws (3200 blocks -> hides the 1.28MB-strided random-read latency that made
// the fused R1 kernel latency-bound at 64 waves), and (b) the serial scan
// reading coalesced from ws.
//
// Tree structure (in-order numbering), p = v+1:
//   START <=> p power of 2; END <=> p + (p&-p) == 256; OUT = non-END.
//   non-START x: s=ctz(p), j=x-2^s, k=ctz(p&(p-1)); sources {j-2^a: a<k}.

#define TT 50
#define BB 64
#define VOCAB 5000
#define NS 255
#define NSP 256
#define LOG_EPS_F (-64.0f)
#define EPS_F 1.6038109389511818e-28f  // exp(-64)
#define WS_NEEDED ((size_t)BB * TT * NSP * 4)

__device__ __forceinline__ float wred_max(float x) {
#pragma unroll
    for (int m = 32; m >= 1; m >>= 1) x = fmaxf(x, __shfl_xor(x, m));
    return x;
}
__device__ __forceinline__ float wred_sum(float x) {
#pragma unroll
    for (int m = 32; m >= 1; m >>= 1) x += __shfl_xor(x, m);
    return x;
}

// ---- Kernel A: extracted[b][t][v] = log_probs[v][b][targets[t][b]] ----
__global__ __launch_bounds__(256) void gather_kernel(
    const float* __restrict__ log_probs,
    const int* __restrict__ targets,
    const int* __restrict__ target_lengths,
    float* __restrict__ ews)
{
    const int bt = blockIdx.x;          // b*TT + t
    const int b = bt / TT;
    const int t = bt % TT;
    if (t >= target_lengths[b]) return; // uniform branch, block exits
    const int v = threadIdx.x;
    const int tgt = targets[t * BB + b];
    float val = -1e30f;                 // pad slot v=255
    if (v < NS)
        val = log_probs[(size_t)v * (BB * VOCAB) + (size_t)b * VOCAB + tgt];
    ews[(size_t)bt * NSP + v] = val;    // coalesced 1KB/wavefront
}

// ---- Kernel B: serial scan, one wave per batch element ----
__global__ __launch_bounds__(64) void scan_kernel(
    const float* __restrict__ ews,
    const int* __restrict__ target_lengths,
    float* __restrict__ out)
{
    const int b = blockIdx.x;
    const int lane = threadIdx.x;
    const int vbase = lane * 4;
    __shared__ float outv[NSP];

    const int len = target_lengths[b];
    const float4* ew = (const float4*)(ews + (size_t)b * TT * NSP);

    // static tree structure for this lane's 4 nodes
    bool isend[4], isout[4];
    int kk[4], jj[4];
    float prev[4];
#pragma unroll
    for (int i = 0; i < 4; ++i) {
        int v = vbase + i;
        int p = v + 1;
        bool valid = (v < NS);
        bool pw2 = (p & (p - 1)) == 0;
        bool e_ = valid && ((p + (p & (-p))) == 256);
        isend[i] = e_;
        isout[i] = valid && !e_;
        prev[i] = (valid && pw2) ? 1.0f : 0.0f;
        if (valid && !pw2) {
            int s = __ffs(p) - 1;
            int q = p & (p - 1);
            kk[i] = __ffs(q) - 1;
            jj[i] = v - (1 << s);
        } else { kk[i] = 0; jj[i] = 0; }
    }

    float acc = 0.0f;
    float4 e4 = ew[lane];               // prefetch t=0
    for (int t = 0; t < len; ++t) {
        float4 cur = e4;
        if (t + 1 < len) e4 = ew[(t + 1) * 64 + lane];   // prefetch next

        float lc[4];
#pragma unroll
        for (int i = 0; i < 4; ++i) {
            float pv = prev[i];
            float lp = (pv < EPS_F) ? LOG_EPS_F : __logf(pv);
            lc[i] = lp + ((const float*)&cur)[i];
        }

        if (t == len - 1) {
            float m = -INFINITY;
#pragma unroll
            for (int i = 0; i < 4; ++i)
                if (isend[i]) m = fmaxf(m, lc[i]);
            m = wred_max(m);
            float s = 0.0f;
#pragma unroll
            for (int i = 0; i < 4; ++i)
                if (isend[i]) s += __expf(lc[i] - m);
            s = wred_sum(s);
            acc += m + __logf(s);
        } else {
            float m = -INFINITY;
#pragma unroll
            for (int i = 0; i < 4; ++i)
                if (isout[i]) m = fmaxf(m, lc[i]);
            m = wred_max(m);
            float s = 0.0f;
#pragma unroll
            for (int i = 0; i < 4; ++i)
                if (isout[i]) s += __expf(lc[i] - m);
            s = wred_sum(s);
            float logC = m + __logf(s);
            acc += logC;

#pragma unroll
            for (int i = 0; i < 4; ++i) {
                float d = lc[i] - logC;
                outv[vbase + i] = (d < LOG_EPS_F) ? EPS_F : __expf(d);
            }
            __syncthreads();
#pragma unroll
            for (int i = 0; i < 4; ++i) {
                float np_ = 0.0f;
                int bj = jj[i];
                int n = kk[i];
                for (int a = 0; a < n; ++a) np_ += outv[bj - (1 << a)];
                prev[i] = np_;
            }
            __syncthreads();
        }
    }
    if (lane == 0) out[b] = -acc;
}

// ---- Fallback: R1 fused kernel (used only if ws too small) ----
__global__ __launch_bounds__(64) void ctreec_fused(
    const float* __restrict__ log_probs,
    const int* __restrict__ targets,
    const int* __restrict__ target_lengths,
    float* __restrict__ out)
{
    const int b = blockIdx.x;
    const int lane = threadIdx.x;
    const int vbase = lane * 4;
    __shared__ float e_lds[TT * NSP];
    __shared__ float outv[NSP];
    __shared__ int tgts[TT];
    const int len = target_lengths[b];
    if (lane < TT) tgts[lane] = targets[lane * BB + b];
    __syncthreads();
    {
        const size_t bvoff = (size_t)b * VOCAB;
        float4* e_vec = (float4*)e_lds;
#pragma unroll 4
        for (int t = 0; t < len; ++t) {
            const float* base = log_probs + bvoff + (size_t)tgts[t];
            float4 val;
            val.x = base[(size_t)(vbase + 0) * (BB * VOCAB)];
            val.y = base[(size_t)(vbase + 1) * (BB * VOCAB)];
            val.z = base[(size_t)(vbase + 2) * (BB * VOCAB)];
            val.w = (vbase + 3 < NS) ? base[(size_t)(vbase + 3) * (BB * VOCAB)] : -1e30f;
            e_vec[t * 64 + lane] = val;
        }
    }
    __syncthreads();
    bool isend[4], isout[4];
    int kk[4], jj[4];
    float prev[4];
#pragma unroll
    for (int i = 0; i < 4; ++i) {
        int v = vbase + i;
        int p = v + 1;
        bool valid = (v < NS);
        bool pw2 = (p & (p - 1)) == 0;
        bool e_ = valid && ((p + (p & (-p))) == 256);
        isend[i] = e_;
        isout[i] = valid && !e_;
        prev[i] = (valid && pw2) ? 1.0f : 0.0f;
        if (valid && !pw2) {
            int s = __ffs(p) - 1;
            int q = p & (p - 1);
            kk[i] = __ffs(q) - 1;
            jj[i] = v - (1 << s);
        } else { kk[i] = 0; jj[i] = 0; }
    }
    const float4* e_vec = (const float4*)e_lds;
    float acc = 0.0f;
    for (int t = 0; t < len; ++t) {
        float4 e4 = e_vec[t * 64 + lane];
        float e[4] = {e4.x, e4.y, e4.z, e4.w};
        float lc[4];
#pragma unroll
        for (int i = 0; i < 4; ++i) {
            float pv = prev[i];
            float lp = (pv < EPS_F) ? LOG_EPS_F : __logf(pv);
            lc[i] = lp + e[i];
        }
        if (t == len - 1) {
            float m = -INFINITY;
#pragma unroll
            for (int i = 0; i < 4; ++i)
                if (isend[i]) m = fmaxf(m, lc[i]);
            m = wred_max(m);
            float s = 0.0f;
#pragma unroll
            for (int i = 0; i < 4; ++i)
                if (isend[i]) s += __expf(lc[i] - m);
            s = wred_sum(s);
            acc += m + __logf(s);
        } else {
            float m = -INFINITY;
#pragma unroll
            for (int i = 0; i < 4; ++i)
                if (isout[i]) m = fmaxf(m, lc[i]);
            m = wred_max(m);
            float s = 0.0f;
#pragma unroll
            for (int i = 0; i < 4; ++i)
                if (isout[i]) s += __expf(lc[i] - m);
            s = wred_sum(s);
            float logC = m + __logf(s);
            acc += logC;
#pragma unroll
            for (int i = 0; i < 4; ++i) {
                float d = lc[i] - logC;
                outv[vbase + i] = (d < LOG_EPS_F) ? EPS_F : __expf(d);
            }
            __syncthreads();
#pragma unroll
            for (int i = 0; i < 4; ++i) {
                float np_ = 0.0f;
                int bj = jj[i];
                int n = kk[i];
                for (int a = 0; a < n; ++a) np_ += outv[bj - (1 << a)];
                prev[i] = np_;
            }
            __syncthreads();
        }
    }
    if (lane == 0) out[b] = -acc;
}

extern "C" void kernel_launch(void* const* d_in, const int* in_sizes, int n_in,
                              void* d_out, int out_size, void* d_ws, size_t ws_size,
                              hipStream_t stream) {
    const float* log_probs = (const float*)d_in[0];       // 255*64*5000
    const int* targets = (const int*)d_in[1];             // 50*64
    const int* target_lengths = (const int*)d_in[2];      // 64
    float* out = (float*)d_out;                           // 64

    if (ws_size >= WS_NEEDED) {
        float* ews = (float*)d_ws;
        gather_kernel<<<dim3(BB * TT), dim3(256), 0, stream>>>(
            log_probs, targets, target_lengths, ews);
        scan_kernel<<<dim3(BB), dim3(64), 0, stream>>>(
            ews, target_lengths, out);
    } else {
        ctreec_fused<<<dim3(BB), dim3(64), 0, stream>>>(
            log_probs, targets, target_lengths, out);
    }
}

// Round 3
// 441.602 us; speedup vs baseline: 1.1079x; 1.0433x over previous
//
#include <hip/hip_runtime.h>
#include <math.h>

// CTreeC loss: DEPTH=7, V=255 states, B=64, T=50, vocab=5000.
// R3: linear-domain scan. The reference's per-step logC normalization
// telescopes: dividing curr by ANY scalar S while adding log(S) to acc leaves
// the result invariant, and the reference's S = sum_OUT(curr) is computable in
// linear space. Per step: 4 muls + one 6-round wave sum-reduce + __logf + rcp.
// exp(extracted) is precomputed in the massively-parallel gather kernel.
// EPS-clamp differences vs reference are ~e-60 relative (invisible in fp32).
//
// Tree structure (in-order numbering), p = v+1:
//   START <=> p power of 2; END <=> p + (p&-p) == 256; OUT = non-END (247).
//   non-START x: s=ctz(p), j=x-2^s, k=ctz(p&(p-1)); sources {j-2^a: a<k}.

#define TT 50
#define BB 64
#define VOCAB 5000
#define NS 255
#define NSP 256
#define LOG_EPS_F (-64.0f)
#define EPS_F 1.6038109389511818e-28f  // exp(-64)
#define WS_NEEDED ((size_t)BB * TT * NSP * 4)

__device__ __forceinline__ float wred_sum(float x) {
#pragma unroll
    for (int m = 32; m >= 1; m >>= 1) x += __shfl_xor(x, m);
    return x;
}
__device__ __forceinline__ float wred_max(float x) {
#pragma unroll
    for (int m = 32; m >= 1; m >>= 1) x = fmaxf(x, __shfl_xor(x, m));
    return x;
}

// ---- Kernel A: ews[b][t][v] = exp(log_probs[v][b][targets[t][b]]) ----
__global__ __launch_bounds__(256) void gather_kernel(
    const float* __restrict__ log_probs,
    const int* __restrict__ targets,
    const int* __restrict__ target_lengths,
    float* __restrict__ ews)
{
    const int bt = blockIdx.x;          // b*TT + t
    const int b = bt / TT;
    const int t = bt % TT;
    if (t >= target_lengths[b]) return; // uniform branch, block exits
    const int v = threadIdx.x;
    const int tgt = targets[t * BB + b];
    float val = 0.0f;                   // pad slot v=255 contributes nothing
    if (v < NS)
        val = __expf(log_probs[(size_t)v * (BB * VOCAB) + (size_t)b * VOCAB + tgt]);
    ews[(size_t)bt * NSP + v] = val;    // coalesced 1KB/wavefront
}

// ---- Kernel B: linear-domain serial scan, one wave per batch element ----
__global__ __launch_bounds__(64) void scan_kernel(
    const float* __restrict__ ews,
    const int* __restrict__ target_lengths,
    float* __restrict__ out)
{
    const int b = blockIdx.x;
    const int lane = threadIdx.x;
    const int vbase = lane * 4;
    __shared__ float outv[NSP];

    const int len = target_lengths[b];
    const float4* ew = (const float4*)(ews + (size_t)b * TT * NSP);

    // static tree structure for this lane's 4 nodes
    bool isend[4], isout[4];
    int kk[4], jj[4];
    float prev[4];
#pragma unroll
    for (int i = 0; i < 4; ++i) {
        int v = vbase + i;
        int p = v + 1;
        bool valid = (v < NS);
        bool pw2 = (p & (p - 1)) == 0;
        bool e_ = valid && ((p + (p & (-p))) == 256);
        isend[i] = e_;
        isout[i] = valid && !e_;
        prev[i] = (valid && pw2) ? 1.0f : 0.0f;
        if (valid && !pw2) {
            int s = __ffs(p) - 1;
            int q = p & (p - 1);
            kk[i] = __ffs(q) - 1;
            jj[i] = v - (1 << s);
        } else { kk[i] = 0; jj[i] = 0; }
    }

    float acc = 0.0f;
    float4 eA = ew[lane];                               // prefetch t, t+1
    float4 eB = (len > 1) ? ew[64 + lane] : eA;
    for (int t = 0; t < len; ++t) {
        float4 cur = eA;
        eA = eB;
        if (t + 2 < len) eB = ew[(t + 2) * 64 + lane];  // prefetch depth 2

        float c[4];
        c[0] = prev[0] * cur.x;
        c[1] = prev[1] * cur.y;
        c[2] = prev[2] * cur.z;
        c[3] = prev[3] * cur.w;

        if (t == len - 1) {
            float s = 0.0f;
#pragma unroll
            for (int i = 0; i < 4; ++i)
                if (isend[i]) s += c[i];
            s = wred_sum(s);
            acc += __logf(s);
        } else {
            // stage unnormalized curr in LDS; overlaps with the reduction
            *(float4*)&outv[vbase] = make_float4(c[0], c[1], c[2], c[3]);
            float s = 0.0f;
#pragma unroll
            for (int i = 0; i < 4; ++i)
                if (isout[i]) s += c[i];
            s = wred_sum(s);
            acc += __logf(s);
            float rinv = 1.0f / s;   // scaling error telescopes out exactly
            __syncthreads();
            // new_prev[x] = rinv * sum over its <=7 sources
#pragma unroll
            for (int i = 0; i < 4; ++i) {
                float np_ = 0.0f;
                int bj = jj[i];
                int n = kk[i];
                for (int a = 0; a < n; ++a) np_ += outv[bj - (1 << a)];
                prev[i] = np_ * rinv;
            }
            __syncthreads();
        }
    }
    if (lane == 0) out[b] = -acc;
}

// ---- Fallback: R1 fused log-domain kernel (used only if ws too small) ----
__global__ __launch_bounds__(64) void ctreec_fused(
    const float* __restrict__ log_probs,
    const int* __restrict__ targets,
    const int* __restrict__ target_lengths,
    float* __restrict__ out)
{
    const int b = blockIdx.x;
    const int lane = threadIdx.x;
    const int vbase = lane * 4;
    __shared__ float e_lds[TT * NSP];
    __shared__ float outv[NSP];
    __shared__ int tgts[TT];
    const int len = target_lengths[b];
    if (lane < TT) tgts[lane] = targets[lane * BB + b];
    __syncthreads();
    {
        const size_t bvoff = (size_t)b * VOCAB;
        float4* e_vec = (float4*)e_lds;
#pragma unroll 4
        for (int t = 0; t < len; ++t) {
            const float* base = log_probs + bvoff + (size_t)tgts[t];
            float4 val;
            val.x = base[(size_t)(vbase + 0) * (BB * VOCAB)];
            val.y = base[(size_t)(vbase + 1) * (BB * VOCAB)];
            val.z = base[(size_t)(vbase + 2) * (BB * VOCAB)];
            val.w = (vbase + 3 < NS) ? base[(size_t)(vbase + 3) * (BB * VOCAB)] : -1e30f;
            e_vec[t * 64 + lane] = val;
        }
    }
    __syncthreads();
    bool isend[4], isout[4];
    int kk[4], jj[4];
    float prev[4];
#pragma unroll
    for (int i = 0; i < 4; ++i) {
        int v = vbase + i;
        int p = v + 1;
        bool valid = (v < NS);
        bool pw2 = (p & (p - 1)) == 0;
        bool e_ = valid && ((p + (p & (-p))) == 256);
        isend[i] = e_;
        isout[i] = valid && !e_;
        prev[i] = (valid && pw2) ? 1.0f : 0.0f;
        if (valid && !pw2) {
            int s = __ffs(p) - 1;
            int q = p & (p - 1);
            kk[i] = __ffs(q) - 1;
            jj[i] = v - (1 << s);
        } else { kk[i] = 0; jj[i] = 0; }
    }
    const float4* e_vec = (const float4*)e_lds;
    float acc = 0.0f;
    for (int t = 0; t < len; ++t) {
        float4 e4 = e_vec[t * 64 + lane];
        float e[4] = {e4.x, e4.y, e4.z, e4.w};
        float lc[4];
#pragma unroll
        for (int i = 0; i < 4; ++i) {
            float pv = prev[i];
            float lp = (pv < EPS_F) ? LOG_EPS_F : __logf(pv);
            lc[i] = lp + e[i];
        }
        if (t == len - 1) {
            float m = -INFINITY;
#pragma unroll
            for (int i = 0; i < 4; ++i)
                if (isend[i]) m = fmaxf(m, lc[i]);
            m = wred_max(m);
            float s = 0.0f;
#pragma unroll
            for (int i = 0; i < 4; ++i)
                if (isend[i]) s += __expf(lc[i] - m);
            s = wred_sum(s);
            acc += m + __logf(s);
        } else {
            float m = -INFINITY;
#pragma unroll
            for (int i = 0; i < 4; ++i)
                if (isout[i]) m = fmaxf(m, lc[i]);
            m = wred_max(m);
            float s = 0.0f;
#pragma unroll
            for (int i = 0; i < 4; ++i)
                if (isout[i]) s += __expf(lc[i] - m);
            s = wred_sum(s);
            float logC = m + __logf(s);
            acc += logC;
#pragma unroll
            for (int i = 0; i < 4; ++i) {
                float d = lc[i] - logC;
                outv[vbase + i] = (d < LOG_EPS_F) ? EPS_F : __expf(d);
            }
            __syncthreads();
#pragma unroll
            for (int i = 0; i < 4; ++i) {
                float np_ = 0.0f;
                int bj = jj[i];
                int n = kk[i];
                for (int a = 0; a < n; ++a) np_ += outv[bj - (1 << a)];
                prev[i] = np_;
            }
            __syncthreads();
        }
    }
    if (lane == 0) out[b] = -acc;
}

extern "C" void kernel_launch(void* const* d_in, const int* in_sizes, int n_in,
                              void* d_out, int out_size, void* d_ws, size_t ws_size,
                              hipStream_t stream) {
    const float* log_probs = (const float*)d_in[0];       // 255*64*5000
    const int* targets = (const int*)d_in[1];             // 50*64
    const int* target_lengths = (const int*)d_in[2];      // 64
    float* out = (float*)d_out;                           // 64

    if (ws_size >= WS_NEEDED) {
        float* ews = (float*)d_ws;
        gather_kernel<<<dim3(BB * TT), dim3(256), 0, stream>>>(
            log_probs, targets, target_lengths, ews);
        scan_kernel<<<dim3(BB), dim3(64), 0, stream>>>(
            ews, target_lengths, out);
    } else {
        ctreec_fused<<<dim3(BB), dim3(64), 0, stream>>>(
            log_probs, targets, target_lengths, out);
    }
}